// Round 1
// baseline (93626.715 us; speedup 1.0000x reference)
//
#include <hip/hip_runtime.h>
#include <math.h>
#include <stdint.h>

// MGU RNN, T=8192, IN=128, H=1024, L=3 — R7: XCD-local recurrence fabric.
//
// Roles by blockIdx&7 (round-robin block->XCD mapping, measured on MI355X):
//   0,1,2 : recurrence layers 0..2 — 64 WGs each, one XCD per layer
//           (512 blk grid, __launch_bounds__(512,4) -> <=128 VGPR -> 2 blk/CU
//            -> 64 co-resident WGs per XCD; all 320 active roles co-resident).
//   3,4   : "army" WGs computing the NON-recurrent input projection
//           gi = w_ih·x + b_ih for layers 1,2 (64 WGs each, on XCDs 3/4),
//           fed by the x-rings, publishing tagged gi-rings via MALL.
//   5,6,7 : exit immediately.
//
// Recurrence step (the serial chain): poll own-layer h via sc0 loads served
// by the XCD-local L2 (producers dual-store sc0+sc1, so a sticky per-thread
// agent-scope fallback is always correct if placement/scope assumptions
// fail); consume depth-2 register-prefetched gi words (tag-checked, classic
// MALL poll fallback); hh-dots only (16 dot4/thread); 2-value reduce; gate.
// Cross-XCD traffic (x-rings, gi-rings, progress) stays on relaxed
// agent-scope atomics exactly as the validated R3-R6 fabric; all overwrite-
// safety arguments (parity-2 h rows, 128-row rings with amortized
// backpressure, barrier-proven consumption) carry over unchanged.
// Tags are strictly increasing -> any stale read can only spin, never
// corrupt; every fast path has a poll fallback -> worst case ~= R6 perf.

#define T_STEPS 8192
#define HDIM 1024
#define RING 128
#define SLACK (RING - 16)
#define HSPIN_FB 4096

typedef unsigned long long u64;
typedef float f32x4 __attribute__((ext_vector_type(4)));

__device__ __forceinline__ u64 agload64(const u64* p) {
    return __hip_atomic_load(p, __ATOMIC_RELAXED, __HIP_MEMORY_SCOPE_AGENT);
}
__device__ __forceinline__ void agstore64(u64* p, u64 v) {
    __hip_atomic_store(p, v, __ATOMIC_RELAXED, __HIP_MEMORY_SCOPE_AGENT);
}
__device__ __forceinline__ int agloadi(const int* p) {
    return __hip_atomic_load(p, __ATOMIC_RELAXED, __HIP_MEMORY_SCOPE_AGENT);
}
__device__ __forceinline__ void agstorei(int* p, int v) {
    __hip_atomic_store(p, v, __ATOMIC_RELAXED, __HIP_MEMORY_SCOPE_AGENT);
}
__device__ __forceinline__ float dot4(float4 a, float4 b) {
    return a.x * b.x + a.y * b.y + a.z * b.z + a.w * b.w;
}
__device__ __forceinline__ u64 pack(float v, int tag) {
    return ((u64)(unsigned)tag << 32) | (u64)__float_as_uint(v);
}
__device__ __forceinline__ void opaque4(float4& v) {
    asm volatile("" : "+v"(v.x), "+v"(v.y), "+v"(v.z), "+v"(v.w));
}
__device__ __forceinline__ void opaque2(float2& v) {
    asm volatile("" : "+v"(v.x), "+v"(v.y));
}

// ---- scope-controlled memory primitives ----
// sc0 load: bypass L1, served by the XCD-local L2 (fast path for same-XCD h).
__device__ __forceinline__ void poll2_sc0(u64& w0, u64& w1,
                                          const u64* p0, const u64* p1) {
    asm volatile("global_load_dwordx2 %0, %2, off sc0\n\t"
                 "global_load_dwordx2 %1, %3, off sc0\n\t"
                 "s_waitcnt vmcnt(0)"
                 : "=&v"(w0), "=&v"(w1)
                 : "v"(p0), "v"(p1)
                 : "memory");
    __builtin_amdgcn_sched_barrier(0);
}
// sc1 load issued WITHOUT a wait: depth-2 prefetch. Value must only be read
// after a fence1/fence2 on the same variable (>=1 full step later).
__device__ __forceinline__ void issue_sc1(u64& d, const u64* p) {
    asm volatile("global_load_dwordx2 %0, %1, off sc1"
                 : "=&v"(d) : "v"(p) : "memory");
}
__device__ __forceinline__ void issue2_sc1(u64& d0, u64& d1,
                                           const u64* p0, const u64* p1) {
    asm volatile("global_load_dwordx2 %0, %2, off sc1\n\t"
                 "global_load_dwordx2 %1, %3, off sc1"
                 : "=&v"(d0), "=&v"(d1)
                 : "v"(p0), "v"(p1)
                 : "memory");
}
__device__ __forceinline__ void fence1(u64& a) {
    asm volatile("s_waitcnt vmcnt(0)" : "+v"(a) :: "memory");
    __builtin_amdgcn_sched_barrier(0);
}
__device__ __forceinline__ void fence2(u64& a, u64& b) {
    asm volatile("s_waitcnt vmcnt(0)" : "+v"(a), "+v"(b) :: "memory");
    __builtin_amdgcn_sched_barrier(0);
}
// dual-scope publish: sc0 -> local L2 (fast consumers), sc1 -> MALL
// (sticky-fallback consumers). Same value twice -> order irrelevant.
__device__ __forceinline__ void pub_dual(u64* p, u64 v) {
    asm volatile("global_store_dwordx2 %0, %1, off sc0\n\t"
                 "global_store_dwordx2 %0, %1, off sc1"
                 :: "v"(p), "v"(v) : "memory");
}

// ================= recurrence step body =================
// Inlined twice per loop iteration so the prefetch slot registers (gS / sS)
// are statically named (an in-flight asm-load destination must never be
// copied/moved before its fence).
template <int L>
__device__ __forceinline__ void rec_body(
    const int t, const int par,
    float* __restrict__ s_h, float* __restrict__ s_x0,
    float (*s_gif)[16], float (*s_gin)[16],
    const int tid, const int a, const int q, const int jb, const int r,
    const float4 (&wf)[2][4], const float4 (&wn)[2][4],
    const float2 (&wif2)[2], const float2 (&win2)[2],
    const float (&bFv)[2], const float (&bInv)[2], const float (&bHnv)[2],
    const float* __restrict__ S, const u64* __restrict__ gi_ring,
    u64* __restrict__ ring_out, float* __restrict__ xout,
    const float* __restrict__ h0, u64* __restrict__ htag,
    int* __restrict__ progNext, int* __restrict__ progSelf,
    int& lastProg, bool& hslow, u64& gS, f32x4& sS)
{
    float* hD = s_h + par * HDIM;
    const u64* hrow = htag + (size_t)((t + 1) & 1) * HDIM;  // parity of t-1
    u64*       hpub = htag + (size_t)(t & 1) * HDIM;

    // ---- amortized ring backpressure (L<2 writes a ring) ----
    if constexpr (L < 2) {
        if (t - lastProg > SLACK) {
            do { lastProg = agloadi(progNext); } while (t - lastProg > SLACK);
        }
    }

    // ---- input acquire: S row (L==0) / prefetched gi words (L>0) ----
    if constexpr (L == 0) {
        float* xD = s_x0 + par * 128;
        if (t < 2) {
            if (tid < 32)
                ((f32x4*)xD)[tid] = ((const f32x4*)(S + (size_t)t * 128))[tid];
        } else {
            if (tid < 32) ((f32x4*)xD)[tid] = sS;  // plain prefetch, 2 steps old
        }
    } else {
        // 32 words (16 units x {f,n}) spread as lanes q<4 of every wave.
        const int gw = a * 4 + q, gu = gw & 15, gpart = gw >> 4;
        if (q < 4) {
            const unsigned xe = (unsigned)(t + 1);
            const u64* p = gi_ring + (size_t)(t & (RING - 1)) * 2048
                         + (size_t)gpart * 1024 + 16 * r + gu;
            u64 w;
            if (t < 2) {
                do { w = agload64(p); } while ((unsigned)(w >> 32) != xe);
            } else {
                fence1(gS);
                w = gS;
                if ((unsigned)(w >> 32) != xe) {   // prefetch missed: classic
                    do { w = agload64(p); } while ((unsigned)(w >> 32) != xe);
                }
            }
            if (gpart == 0) s_gif[par][gu] = __uint_as_float((unsigned)w);
            else            s_gin[par][gu] = __uint_as_float((unsigned)w);
        }
    }

    // ---- h acquire: XCD-local sc0 poll, sticky agent-scope fallback ----
    if (t == 0) {
        hD[tid]       = h0[tid];
        hD[tid + 512] = h0[tid + 512];
    } else {
        const unsigned he = (unsigned)t;
        const u64* p0 = hrow + tid;
        const u64* p1 = hrow + tid + 512;
        u64 hw0 = 0, hw1 = 0;
        bool done = false;
        if (!hslow) {
            int spins = 0;
            for (;;) {
                poll2_sc0(hw0, hw1, p0, p1);
                if ((unsigned)(hw0 >> 32) == he && (unsigned)(hw1 >> 32) == he) {
                    done = true; break;
                }
                if (++spins > HSPIN_FB) { hslow = true; break; }  // sticky
            }
        }
        if (!done) {  // agent-scope classic poll (fed by the sc1 half-store)
            bool d0 = false, d1 = false;
            while (!(d0 && d1)) {
                if (!d0) { hw0 = agload64(p0); d0 = ((unsigned)(hw0 >> 32) == he); }
                if (!d1) { hw1 = agload64(p1); d1 = ((unsigned)(hw1 >> 32) == he); }
            }
        }
        hD[tid]       = __uint_as_float((unsigned)hw0);
        hD[tid + 512] = __uint_as_float((unsigned)hw1);
    }

    // ---- reissue depth-2 prefetch for step t+2 (after the h poll, so the
    //      poll's vmcnt(0) never waits on a fresh MALL load) ----
    if constexpr (L == 0) {
        if (tid < 32) {
            int tn = t + 2; if (tn > T_STEPS - 1) tn = T_STEPS - 1;
            sS = ((const f32x4*)(S + (size_t)tn * 128))[tid];
        }
    } else {
        const int gw = a * 4 + q, gu = gw & 15, gpart = gw >> 4;
        if (q < 4) {
            const u64* p = gi_ring + (size_t)((t + 2) & (RING - 1)) * 2048
                         + (size_t)gpart * 1024 + 16 * r + gu;
            issue_sc1(gS, p);
        }
    }

    __syncthreads();   // the ONE barrier per step

    if constexpr (L > 0) {
        if (r == 0 && tid == 0) agstorei(progSelf, t + 1);
    }

    // ---- hh dots (16 dot4/thread; L0 adds its tiny K=128 x-part) ----
    float aF[2]  = {0.f, 0.f};
    float aNh[2] = {0.f, 0.f};
    float aNi[2] = {0.f, 0.f};
#pragma unroll
    for (int m = 0; m < 4; ++m) {
        const float4 h4 = ((const float4*)hD)[q + 64 * m];
#pragma unroll
        for (int g = 0; g < 2; ++g) {
            aF[g]  += dot4(wf[g][m], h4);
            aNh[g] += dot4(wn[g][m], h4);
        }
    }
    if constexpr (L == 0) {
        const float* xD = s_x0 + par * 128;
        const float2 x2 = *(const float2*)&xD[2 * q];
#pragma unroll
        for (int g = 0; g < 2; ++g) {
            aF[g]  += wif2[g].x * x2.x + wif2[g].y * x2.y;
            aNi[g] += win2[g].x * x2.x + win2[g].y * x2.y;
        }
    }

    // ---- two-phase reduction ----
#pragma unroll
    for (int g = 0; g < 2; ++g) {
        aF[g]  += __shfl_xor(aF[g],  1, 64);
        aNh[g] += __shfl_xor(aNh[g], 1, 64);
        if constexpr (L == 0) aNi[g] += __shfl_xor(aNi[g], 1, 64);
    }
    const int gsl = q & 1;
    float vF  = gsl ? aF[1]  : aF[0];
    float vNh = gsl ? aNh[1] : aNh[0];
    float vNi = 0.f;
    if constexpr (L == 0) vNi = gsl ? aNi[1] : aNi[0];
#pragma unroll
    for (int off = 2; off <= 32; off <<= 1) {
        vF  += __shfl_xor(vF,  off, 64);
        vNh += __shfl_xor(vNh, off, 64);
        if constexpr (L == 0) vNi += __shfl_xor(vNi, off, 64);
    }

    // ---- gate + publish ----
    if (q < 2) {
        const int   j  = jb + q;
        const float hp = hD[j];
        float f, n;
        if constexpr (L == 0) {
            const float cF  = gsl ? bFv[1]  : bFv[0];
            const float cIn = gsl ? bInv[1] : bInv[0];
            const float cHn = gsl ? bHnv[1] : bHnv[0];
            f = 1.f / (1.f + expf(-(vF + cF)));
            n = tanhf(vNi + cIn + f * (vNh + cHn));
        } else {
            const float cHf = gsl ? bFv[1]  : bFv[0];   // b_hh forget part
            const float cHn = gsl ? bHnv[1] : bHnv[0];  // b_hh new part
            const float gf  = s_gif[par][2 * a + q];    // w_ih·x + b_ih (f)
            const float gn  = s_gin[par][2 * a + q];    // w_ih·x + b_ih (n)
            f = 1.f / (1.f + expf(-(gf + vF + cHf)));
            n = tanhf(gn + f * (vNh + cHn));
        }
        const float hy = n + (1.f - f) * (hp - n);
        const u64   pk = pack(hy, t + 1);
        pub_dual(hpub + j, pk);
        if constexpr (L < 2) {
            agstore64(ring_out + (size_t)(t & (RING - 1)) * HDIM + j, pk);
        } else {
            xout[(size_t)t * HDIM + j] = hy;
        }
    }
}

template <int L>
__device__ void rec_layer(float* s_h, float* s_x0,
                          float (*s_gif)[16], float (*s_gin)[16],
                          const float* S, const float* h0,
                          const float* w_ih, const float* b_ih,
                          const float* w_hh, const float* b_hh,
                          const u64* gi_ring, u64* ring_out, float* xout,
                          u64* htag, int* progNext, int* progSelf, int r)
{
    const int tid = threadIdx.x;
    const int a   = tid >> 6;
    const int q   = tid & 63;
    const int jb  = r * 16 + 2 * a;

    // hh weights -> VGPRs (64 floats/thread), pinned opaque
    float4 wf[2][4], wn[2][4];
#pragma unroll
    for (int g = 0; g < 2; ++g) {
        const float* rf = w_hh + (size_t)(jb + g) * HDIM;
        const float* rn = w_hh + (size_t)(HDIM + jb + g) * HDIM;
#pragma unroll
        for (int m = 0; m < 4; ++m) {
            wf[g][m] = *(const float4*)(rf + 4 * q + 256 * m);
            wn[g][m] = *(const float4*)(rn + 4 * q + 256 * m);
            opaque4(wf[g][m]); opaque4(wn[g][m]);
        }
    }
    float2 wif2[2] = {}, win2[2] = {};
    float bFv[2], bInv[2] = {0.f, 0.f}, bHnv[2];
    if constexpr (L == 0) {
#pragma unroll
        for (int g = 0; g < 2; ++g) {
            wif2[g] = *(const float2*)(w_ih + (size_t)(jb + g) * 128 + 2 * q);
            win2[g] = *(const float2*)(w_ih + (size_t)(HDIM + jb + g) * 128 + 2 * q);
            opaque2(wif2[g]); opaque2(win2[g]);
            bFv[g]  = b_ih[jb + g] + b_hh[jb + g];
            bInv[g] = b_ih[HDIM + jb + g];
            bHnv[g] = b_hh[HDIM + jb + g];
        }
    } else {
#pragma unroll
        for (int g = 0; g < 2; ++g) {
            bFv[g]  = b_hh[jb + g];
            bHnv[g] = b_hh[HDIM + jb + g];
        }
    }

    int  lastProg = 0;
    bool hslow    = false;
    u64   gA = 0, gB = 0;     // gi prefetch slots (even/odd steps)
    f32x4 sA = {}, sB = {};   // S-row prefetch slots (L==0)

    for (int t2 = 0; t2 < T_STEPS; t2 += 2) {
        rec_body<L>(t2,     0, s_h, s_x0, s_gif, s_gin, tid, a, q, jb, r,
                    wf, wn, wif2, win2, bFv, bInv, bHnv,
                    S, gi_ring, ring_out, xout, h0, htag,
                    progNext, progSelf, lastProg, hslow, gA, sA);
        rec_body<L>(t2 + 1, 1, s_h, s_x0, s_gif, s_gin, tid, a, q, jb, r,
                    wf, wn, wif2, win2, bFv, bInv, bHnv,
                    S, gi_ring, ring_out, xout, h0, htag,
                    progNext, progSelf, lastProg, hslow, gB, sB);
    }
}

// ================= army (input-projection GEMV) =================
__device__ __forceinline__ void army_body(
    const int t, const int par, float* __restrict__ s_x,
    const int tid, const int a, const int q, const int jb, const int r,
    const float4 (&wiF)[2][4], const float4 (&wiN)[2][4],
    const float (&bIF)[2], const float (&bIN)[2],
    const u64* __restrict__ xring_in, u64* __restrict__ gi_ring,
    int* __restrict__ progNext, int* __restrict__ progSelf,
    int& lastProg, u64& x0s, u64& x1s)
{
    float* xD = s_x + par * HDIM;

    // gi-ring backpressure on recurrence progress
    if (t - lastProg > SLACK) {
        do { lastProg = agloadi(progNext); } while (t - lastProg > SLACK);
    }

    // x acquire (depth-2 prefetched, tag-checked, classic fallback)
    const unsigned xe = (unsigned)(t + 1);
    const u64* xrow = xring_in + (size_t)(t & (RING - 1)) * HDIM;
    u64 w0 = 0, w1 = 0;
    if (t < 2) {
        bool e0 = false, e1 = false;
        while (!(e0 && e1)) {
            if (!e0) { w0 = agload64(xrow + tid);       e0 = ((unsigned)(w0 >> 32) == xe); }
            if (!e1) { w1 = agload64(xrow + tid + 512); e1 = ((unsigned)(w1 >> 32) == xe); }
        }
    } else {
        fence2(x0s, x1s);
        w0 = x0s; w1 = x1s;
        bool e0 = ((unsigned)(w0 >> 32) == xe);
        bool e1 = ((unsigned)(w1 >> 32) == xe);
        while (!(e0 && e1)) {
            if (!e0) { w0 = agload64(xrow + tid);       e0 = ((unsigned)(w0 >> 32) == xe); }
            if (!e1) { w1 = agload64(xrow + tid + 512); e1 = ((unsigned)(w1 >> 32) == xe); }
        }
    }
    xD[tid]       = __uint_as_float((unsigned)w0);
    xD[tid + 512] = __uint_as_float((unsigned)w1);

    {   // reissue prefetch for t+2
        const u64* nrow = xring_in + (size_t)((t + 2) & (RING - 1)) * HDIM;
        issue2_sc1(x0s, x1s, nrow + tid, nrow + tid + 512);
    }

    __syncthreads();
    if (r == 0 && tid == 0) agstorei(progSelf, t + 1);  // x_t consumed

    float aGF[2] = {0.f, 0.f}, aGN[2] = {0.f, 0.f};
#pragma unroll
    for (int m = 0; m < 4; ++m) {
        const float4 x4 = ((const float4*)xD)[q + 64 * m];
#pragma unroll
        for (int g = 0; g < 2; ++g) {
            aGF[g] += dot4(wiF[g][m], x4);
            aGN[g] += dot4(wiN[g][m], x4);
        }
    }
#pragma unroll
    for (int g = 0; g < 2; ++g) {
        aGF[g] += __shfl_xor(aGF[g], 1, 64);
        aGN[g] += __shfl_xor(aGN[g], 1, 64);
    }
    const int gsl = q & 1;
    float vGF = gsl ? aGF[1] : aGF[0];
    float vGN = gsl ? aGN[1] : aGN[0];
#pragma unroll
    for (int off = 2; off <= 32; off <<= 1) {
        vGF += __shfl_xor(vGF, off, 64);
        vGN += __shfl_xor(vGN, off, 64);
    }
    if (q < 2) {
        const int j = jb + q;
        u64* grow = gi_ring + (size_t)(t & (RING - 1)) * 2048;
        const float bf = gsl ? bIF[1] : bIF[0];
        const float bn = gsl ? bIN[1] : bIN[0];
        agstore64(grow + j,        pack(vGF + bf, t + 1));
        agstore64(grow + 1024 + j, pack(vGN + bn, t + 1));
    }
}

__device__ void army_layer(float* s_x, const u64* xring_in, u64* gi_ring,
                           const float* w_ih, const float* b_ih,
                           int* progNext, int* progSelf, int r)
{
    const int tid = threadIdx.x;
    const int a   = tid >> 6;
    const int q   = tid & 63;
    const int jb  = r * 16 + 2 * a;

    float4 wiF[2][4], wiN[2][4];
#pragma unroll
    for (int g = 0; g < 2; ++g) {
        const float* rf = w_ih + (size_t)(jb + g) * HDIM;
        const float* rn = w_ih + (size_t)(HDIM + jb + g) * HDIM;
#pragma unroll
        for (int m = 0; m < 4; ++m) {
            wiF[g][m] = *(const float4*)(rf + 4 * q + 256 * m);
            wiN[g][m] = *(const float4*)(rn + 4 * q + 256 * m);
            opaque4(wiF[g][m]); opaque4(wiN[g][m]);
        }
    }
    float bIF[2], bIN[2];
#pragma unroll
    for (int g = 0; g < 2; ++g) {
        bIF[g] = b_ih[jb + g];
        bIN[g] = b_ih[HDIM + jb + g];
    }

    int lastProg = 0;
    u64 xA0 = 0, xA1 = 0, xB0 = 0, xB1 = 0;

    for (int t2 = 0; t2 < T_STEPS; t2 += 2) {
        army_body(t2,     0, s_x, tid, a, q, jb, r, wiF, wiN, bIF, bIN,
                  xring_in, gi_ring, progNext, progSelf, lastProg, xA0, xA1);
        army_body(t2 + 1, 1, s_x, tid, a, q, jb, r, wiF, wiN, bIF, bIN,
                  xring_in, gi_ring, progNext, progSelf, lastProg, xB0, xB1);
    }
}

// ================= kernels =================
__global__ __launch_bounds__(512, 4)   // <=128 VGPR -> 2 blocks/CU -> all
void mgu_pipe(const float* __restrict__ S,        // 512 blocks co-resident
              const float* __restrict__ h0,
              const float* __restrict__ w_ih0, const float* __restrict__ b_ih0,
              const float* __restrict__ w_hh0, const float* __restrict__ b_hh0,
              const float* __restrict__ w_ih_r, const float* __restrict__ b_ih_r,
              const float* __restrict__ w_hh_r, const float* __restrict__ b_hh_r,
              float* __restrict__ xbuf2, u64* __restrict__ ring0,
              u64* __restrict__ ring1, u64* __restrict__ gi1,
              u64* __restrict__ gi2, u64* __restrict__ htag,
              int* __restrict__ prog)
{
    __shared__ __align__(16) float s_main[2 * HDIM];  // rec: h / army: x
    __shared__ __align__(16) float s_x0[2 * 128];     // L0 S-row staging
    __shared__ float s_gif[2][16];
    __shared__ float s_gin[2][16];

    const int role = blockIdx.x & 7;   // == XCD under round-robin dispatch
    const int r    = blockIdx.x >> 3;  // rank within role, 0..63

    if (role == 0) {
        rec_layer<0>(s_main, s_x0, s_gif, s_gin, S, h0,
                     w_ih0, b_ih0, w_hh0, b_hh0,
                     nullptr, ring0, nullptr,
                     htag, prog + 32, nullptr, r);
    } else if (role == 1) {
        rec_layer<1>(s_main, nullptr, s_gif, s_gin, nullptr, h0 + HDIM,
                     nullptr, nullptr, w_hh_r, b_hh_r,
                     gi1, ring1, nullptr,
                     htag + 2 * HDIM, prog + 96, prog + 64, r);
    } else if (role == 2) {
        rec_layer<2>(s_main, nullptr, s_gif, s_gin, nullptr, h0 + 2 * HDIM,
                     nullptr, nullptr, w_hh_r + 2048 * 1024, b_hh_r + 2048,
                     gi2, nullptr, xbuf2,
                     htag + 4 * HDIM, nullptr, prog + 128, r);
    } else if (role == 3) {
        army_layer(s_main, ring0, gi1, w_ih_r, b_ih_r,
                   prog + 64, prog + 32, r);
    } else if (role == 4) {
        army_layer(s_main, ring1, gi2, w_ih_r + 2048 * 1024, b_ih_r + 2048,
                   prog + 128, prog + 96, r);
    }
    // roles 5..7: exit immediately
}

__global__ __launch_bounds__(256)
void mgu_out(const float* __restrict__ x,       // [T, H]
             const float* __restrict__ w_out,   // [1, H]
             const float* __restrict__ b_out,   // [1]
             float* __restrict__ out)           // [T]
{
    const int wave = threadIdx.x >> 6;
    const int lane = threadIdx.x & 63;
    const int t = blockIdx.x * 4 + wave;
    float acc = 0.f;
#pragma unroll
    for (int m = 0; m < 4; ++m) {
        const int i4 = lane + 64 * m;
        const float4 x4 = ((const float4*)(x + (size_t)t * HDIM))[i4];
        const float4 w4 = ((const float4*)w_out)[i4];
        acc += dot4(x4, w4);
    }
#pragma unroll
    for (int off = 32; off > 0; off >>= 1) acc += __shfl_xor(acc, off, 64);
    if (lane == 0) out[t] = acc + b_out[0];
}

extern "C" void kernel_launch(void* const* d_in, const int* in_sizes, int n_in,
                              void* d_out, int out_size, void* d_ws, size_t ws_size,
                              hipStream_t stream) {
    const float* S      = (const float*)d_in[0];   // [8192,128]
    const float* h0     = (const float*)d_in[1];   // [3,1024]
    const float* w_ih0  = (const float*)d_in[2];   // [2048,128]
    const float* w_hh0  = (const float*)d_in[3];   // [2048,1024]
    const float* b_ih0  = (const float*)d_in[4];   // [2048]
    const float* b_hh0  = (const float*)d_in[5];   // [2048]
    const float* w_ih_r = (const float*)d_in[6];   // [2,2048,1024]
    const float* w_hh_r = (const float*)d_in[7];   // [2,2048,1024]
    const float* b_ih_r = (const float*)d_in[8];   // [2,2048]
    const float* b_hh_r = (const float*)d_in[9];   // [2,2048]
    const float* w_out  = (const float*)d_in[10];  // [1,1024]
    const float* b_out  = (const float*)d_in[11];  // [1]
    float* out = (float*)d_out;                    // [8192]

    char* ws = (char*)d_ws;
    float* xbuf2 = (float*)(ws);                        // 32 MB [T,H] f32
    u64*   ring0 = (u64*)(ws + (32u << 20));            // 1 MB  [RING,H] u64
    u64*   ring1 = (u64*)(ws + (33u << 20));            // 1 MB
    u64*   gi1   = (u64*)(ws + (34u << 20));            // 2 MB  [RING,2H] u64
    u64*   gi2   = (u64*)(ws + (36u << 20));            // 2 MB
    u64*   htag  = (u64*)(ws + (38u << 20));            // 3 x [2,H] u64
    int*   prog  = (int*)(ws + (38u << 20) + (64u << 10));

    // No init kernel: all tags/progress use exact-match vs the 0xAA poison.
    mgu_pipe<<<512, 512, 0, stream>>>(S, h0, w_ih0, b_ih0, w_hh0, b_hh0,
                                      w_ih_r, b_ih_r, w_hh_r, b_hh_r,
                                      xbuf2, ring0, ring1, gi1, gi2,
                                      htag, prog);
    mgu_out<<<2048, 256, 0, stream>>>(xbuf2, w_out, b_out, out);
}

// Round 2
// 25068.484 us; speedup vs baseline: 3.7348x; 3.7348x over previous
//
#include <hip/hip_runtime.h>
#include <math.h>
#include <stdint.h>

// MGU RNN, T=8192, IN=128, H=1024, L=3 — R8: R6 fabric + army offload.
//
// Lesson from R7 (4x regression): __launch_bounds__(512,4) capped waves at
// 128 unified regs -> hot weight state spilled and was reloaded every step.
// R8 returns to the PROVEN R6 sync fabric (relaxed agent-scope tagged words,
// exact-match tags vs 0xAA poison, one barrier/step, parity-2 h rows,
// 128-row rings, amortized backpressure) and keeps exactly ONE structural
// change: the non-recurrent input projection gi = w_ih·x + b_ih of layers
// 1/2 moves to dedicated "army" WGs fed by the x-rings. Recurrence layers
// then run hh-dots only (half the dot work), poll no x, and reduce 2 values.
//
// Sizing is chosen so register safety is guaranteed by launch bounds, not
// luck: 256-thread WGs, __launch_bounds__(256,2) -> 256-reg cap/wave and
// EXACTLY 2 blocks/CU -> the 512-block grid is fully co-resident.
//   blocks   0..127 : rec layer 0 (8 units/WG, 2/wave; inline K=128 ih)
//   blocks 128..255 : rec layer 1 (hh only + gi poll)
//   blocks 256..383 : rec layer 2 (hh only + gi poll, writes xbuf2)
//   blocks 384..447 : army for layer 1 (consumes ring0, publishes gi1)
//   blocks 448..511 : army for layer 2 (consumes ring1, publishes gi2)
//
// New safety requirement introduced by the army: army WGs are NOT coupled
// to each other step-by-step (rec WGs are, via the h all-to-all), so one
// WG's progress cannot bound the group. Each army WG publishes its own
// progress word; the x-ring producer throttles on a 64-lane shuffle-MIN
// over all 64 words. Progress snapshots are monotone, so a stale MIN is
// conservative -> overwrite-safe. All other overwrite arguments are R6's.

#define T_STEPS 8192
#define HDIM 1024
#define RING 128
#define SLACK (RING - 16)

typedef unsigned long long u64;

__device__ __forceinline__ u64 agload64(const u64* p) {
    return __hip_atomic_load(p, __ATOMIC_RELAXED, __HIP_MEMORY_SCOPE_AGENT);
}
__device__ __forceinline__ void agstore64(u64* p, u64 v) {
    __hip_atomic_store(p, v, __ATOMIC_RELAXED, __HIP_MEMORY_SCOPE_AGENT);
}
__device__ __forceinline__ int agloadi(const int* p) {
    return __hip_atomic_load(p, __ATOMIC_RELAXED, __HIP_MEMORY_SCOPE_AGENT);
}
__device__ __forceinline__ void agstorei(int* p, int v) {
    __hip_atomic_store(p, v, __ATOMIC_RELAXED, __HIP_MEMORY_SCOPE_AGENT);
}
__device__ __forceinline__ float dot4(float4 a, float4 b) {
    return a.x * b.x + a.y * b.y + a.z * b.z + a.w * b.w;
}
__device__ __forceinline__ u64 pack(float v, int tag) {
    return ((u64)(unsigned)tag << 32) | (u64)__float_as_uint(v);
}
__device__ __forceinline__ void opaque4(float4& v) {
    asm volatile("" : "+v"(v.x), "+v"(v.y), "+v"(v.z), "+v"(v.w));
}
__device__ __forceinline__ void opaque2(float2& v) {
    asm volatile("" : "+v"(v.x), "+v"(v.y));
}

// MIN over a 64-int per-WG progress array, computed redundantly by every
// wave (lane q reads word q). Snapshots are monotone-increasing, so any
// wave's stale MIN is a conservative (safe) bound; waves may diverge in
// their throttle decision without hazard.
__device__ __forceinline__ int minscan64(const int* parr, int q) {
    int p = agloadi(parr + q);
#pragma unroll
    for (int off = 32; off; off >>= 1) {
        const int o = __shfl_xor(p, off, 64);
        p = p < o ? p : o;
    }
    return p;
}

// ================= recurrence layer =================
// 128 WGs x 256 threads. WG r owns units [8r, 8r+8); wave a owns 2 units
// jb = 8r + 2a, jb+1. Per-thread hh weights: 64 floats (16 float4).
template <int L>
__device__ void rec_layer(float* __restrict__ s_h,        // LDS [2][1024]
                          float* __restrict__ s_x0,       // LDS [2][128] (L0)
                          float (*__restrict__ s_gi)[16], // LDS [2][16]  (L>0)
                          const float* __restrict__ S,
                          const float* __restrict__ h0,
                          const float* __restrict__ w_ih,
                          const float* __restrict__ b_ih,
                          const float* __restrict__ w_hh,
                          const float* __restrict__ b_hh,
                          const u64* __restrict__ giRing,  // L>0
                          u64* __restrict__ ring_out,      // L<2
                          float* __restrict__ xout,        // L==2
                          u64* __restrict__ htag,          // [2][1024]
                          const int* __restrict__ progArr, // L<2: 64 words
                          int* __restrict__ progGiSelf,    // L>0: 1 word
                          int r)
{
    const int tid = threadIdx.x;       // 0..255
    const int a   = tid >> 6;          // wave 0..3
    const int q   = tid & 63;
    const int jb  = r * 8 + 2 * a;

    // ---- hh weights -> VGPRs (64 floats/thread), pinned opaque ----
    float4 wf[2][4], wn[2][4];
#pragma unroll
    for (int g = 0; g < 2; ++g) {
        const float* rf = w_hh + (size_t)(jb + g) * HDIM;
        const float* rn = w_hh + (size_t)(HDIM + jb + g) * HDIM;
#pragma unroll
        for (int m = 0; m < 4; ++m) {
            wf[g][m] = *(const float4*)(rf + 4 * q + 256 * m);
            wn[g][m] = *(const float4*)(rn + 4 * q + 256 * m);
            opaque4(wf[g][m]); opaque4(wn[g][m]);
        }
    }
    float2 wif2[2] = {}, win2[2] = {};
    float bFv[2], bInv[2] = {0.f, 0.f}, bHnv[2];
    if constexpr (L == 0) {
#pragma unroll
        for (int g = 0; g < 2; ++g) {
            wif2[g] = *(const float2*)(w_ih + (size_t)(jb + g) * 128 + 2 * q);
            win2[g] = *(const float2*)(w_ih + (size_t)(HDIM + jb + g) * 128 + 2 * q);
            opaque2(wif2[g]); opaque2(win2[g]);
            bFv[g]  = b_ih[jb + g] + b_hh[jb + g];
            bInv[g] = b_ih[HDIM + jb + g];
            bHnv[g] = b_hh[HDIM + jb + g];
        }
    } else {
#pragma unroll
        for (int g = 0; g < 2; ++g) {
            bFv[g]  = b_hh[jb + g];          // hh forget bias
            bHnv[g] = b_hh[HDIM + jb + g];   // hh new bias
        }
    }

    int lastProg = 0;

    for (int t = 0; t < T_STEPS; ++t) {
        const int par = t & 1;
        float* hD = s_h + par * HDIM;
        const u64* hrow = htag + (size_t)((t + 1) & 1) * HDIM;  // h_{t-1}
        u64*       hpub = htag + (size_t)par * HDIM;

        // ---- ring backpressure vs army per-WG progress MIN (L<2) ----
        if constexpr (L < 2) {
            if (t - lastProg > SLACK) {
                do { lastProg = minscan64(progArr, q); }
                while (t - lastProg > SLACK);
            }
        }

        // ---- input acquire ----
        if constexpr (L == 0) {
            float* xD = s_x0 + par * 128;
            if (tid < 32)
                ((float4*)xD)[tid] = ((const float4*)(S + (size_t)t * 128))[tid];
        } else {
            // 16 gi words/WG (8 f + 8 n); ready in steady state (army ahead)
            if (tid < 16) {
                const unsigned xe = (unsigned)(t + 1);
                const u64* p = giRing + (size_t)(t & (RING - 1)) * 2048
                             + (tid < 8 ? (size_t)(8 * r + tid)
                                        : (size_t)(1024 + 8 * r + (tid - 8)));
                u64 w;
                do { w = agload64(p); } while ((unsigned)(w >> 32) != xe);
                s_gi[par][tid] = __uint_as_float((unsigned)w);
            }
        }

        // ---- h acquire: 4 tagged words/thread ----
        if (t == 0) {
            hD[tid]       = h0[tid];
            hD[tid + 256] = h0[tid + 256];
            hD[tid + 512] = h0[tid + 512];
            hD[tid + 768] = h0[tid + 768];
        } else {
            const unsigned he = (unsigned)t;
            u64 w0 = 0, w1 = 0, w2 = 0, w3 = 0;
            bool d0 = false, d1 = false, d2 = false, d3 = false;
            while (!(d0 && d1 && d2 && d3)) {
                if (!d0) { w0 = agload64(hrow + tid);       d0 = ((unsigned)(w0 >> 32) == he); }
                if (!d1) { w1 = agload64(hrow + tid + 256); d1 = ((unsigned)(w1 >> 32) == he); }
                if (!d2) { w2 = agload64(hrow + tid + 512); d2 = ((unsigned)(w2 >> 32) == he); }
                if (!d3) { w3 = agload64(hrow + tid + 768); d3 = ((unsigned)(w3 >> 32) == he); }
            }
            hD[tid]       = __uint_as_float((unsigned)w0);
            hD[tid + 256] = __uint_as_float((unsigned)w1);
            hD[tid + 512] = __uint_as_float((unsigned)w2);
            hD[tid + 768] = __uint_as_float((unsigned)w3);
        }
        __syncthreads();   // the ONE barrier per step

        // gi consumption progress: r0's barrier + h-coupling bounds all WGs
        if constexpr (L > 0) {
            if (r == 0 && tid == 0) agstorei(progGiSelf, t + 1);
        }

        // ---- hh dots (16 dot4/thread; L0 adds its K=128 x-part) ----
        float aF[2]  = {0.f, 0.f};
        float aNh[2] = {0.f, 0.f};
        float aNi[2] = {0.f, 0.f};
#pragma unroll
        for (int m = 0; m < 4; ++m) {
            const float4 h4 = ((const float4*)hD)[q + 64 * m];
#pragma unroll
            for (int g = 0; g < 2; ++g) {
                aF[g]  += dot4(wf[g][m], h4);
                aNh[g] += dot4(wn[g][m], h4);
            }
        }
        if constexpr (L == 0) {
            const float* xD = s_x0 + par * 128;
            const float2 x2 = *(const float2*)&xD[2 * q];
#pragma unroll
            for (int g = 0; g < 2; ++g) {
                aF[g]  += wif2[g].x * x2.x + wif2[g].y * x2.y;
                aNi[g] += win2[g].x * x2.x + win2[g].y * x2.y;
            }
        }

        // ---- two-phase reduction (2 units/wave) ----
#pragma unroll
        for (int g = 0; g < 2; ++g) {
            aF[g]  += __shfl_xor(aF[g],  1, 64);
            aNh[g] += __shfl_xor(aNh[g], 1, 64);
            if constexpr (L == 0) aNi[g] += __shfl_xor(aNi[g], 1, 64);
        }
        const int gsl = q & 1;
        float vF  = gsl ? aF[1]  : aF[0];
        float vNh = gsl ? aNh[1] : aNh[0];
        float vNi = 0.f;
        if constexpr (L == 0) vNi = gsl ? aNi[1] : aNi[0];
#pragma unroll
        for (int off = 2; off <= 32; off <<= 1) {
            vF  += __shfl_xor(vF,  off, 64);
            vNh += __shfl_xor(vNh, off, 64);
            if constexpr (L == 0) vNi += __shfl_xor(vNi, off, 64);
        }

        // ---- gate + publish: lane 0 -> unit jb, lane 1 -> unit jb+1 ----
        if (q < 2) {
            const int   j  = jb + q;
            const float hp = hD[j];
            float f, n;
            if constexpr (L == 0) {
                const float cF  = gsl ? bFv[1]  : bFv[0];
                const float cIn = gsl ? bInv[1] : bInv[0];
                const float cHn = gsl ? bHnv[1] : bHnv[0];
                f = 1.f / (1.f + expf(-(vF + cF)));
                n = tanhf(vNi + cIn + f * (vNh + cHn));
            } else {
                const float cHf = gsl ? bFv[1]  : bFv[0];
                const float cHn = gsl ? bHnv[1] : bHnv[0];
                const float gf  = s_gi[par][2 * a + q];       // ih f + b_ih
                const float gn  = s_gi[par][8 + 2 * a + q];   // ih n + b_ih
                f = 1.f / (1.f + expf(-(gf + vF + cHf)));
                n = tanhf(gn + f * (vNh + cHn));
            }
            const float hy = n + (1.f - f) * (hp - n);
            const u64   pk = pack(hy, t + 1);
            agstore64(hpub + j, pk);
            if constexpr (L < 2) {
                agstore64(ring_out + (size_t)(t & (RING - 1)) * HDIM + j, pk);
            } else {
                xout[(size_t)t * HDIM + j] = hy;
            }
        }
        // no trailing barrier: parity LDS buffers bound intra-WG skew to 1.
    }
}

// ================= army (input-projection GEMV) =================
// 64 WGs x 256 threads per layer. WG r owns units [16r, 16r+16); wave a
// owns 4 units jb..jb+3 (jb = 16r + 4a). 128 weight floats/thread — safe
// under the 256-reg cap of __launch_bounds__(256,2).
__device__ void army_layer(float* __restrict__ s_x,        // LDS [2][1024]
                           const u64* __restrict__ xring,
                           u64* __restrict__ giRing,
                           const float* __restrict__ w_ih,
                           const float* __restrict__ b_ih,
                           const int* __restrict__ progGiNext, // 1 word
                           int* __restrict__ progSelf,         // own word
                           int r)
{
    const int tid = threadIdx.x;
    const int a   = tid >> 6;
    const int q   = tid & 63;
    const int jb  = r * 16 + 4 * a;

    float4 wiF[4][4], wiN[4][4];
#pragma unroll
    for (int g = 0; g < 4; ++g) {
        const float* rf = w_ih + (size_t)(jb + g) * HDIM;
        const float* rn = w_ih + (size_t)(HDIM + jb + g) * HDIM;
#pragma unroll
        for (int m = 0; m < 4; ++m) {
            wiF[g][m] = *(const float4*)(rf + 4 * q + 256 * m);
            wiN[g][m] = *(const float4*)(rn + 4 * q + 256 * m);
            opaque4(wiF[g][m]); opaque4(wiN[g][m]);
        }
    }
    float bIF[4], bIN[4];
#pragma unroll
    for (int g = 0; g < 4; ++g) {
        bIF[g] = b_ih[jb + g];
        bIN[g] = b_ih[HDIM + jb + g];
    }

    int lastProg = 0;

    for (int t = 0; t < T_STEPS; ++t) {
        const int par = t & 1;
        float* xD = s_x + par * HDIM;

        // gi-ring backpressure on the consumer layer's progress
        if (t - lastProg > SLACK) {
            do { lastProg = agloadi(progGiNext); } while (t - lastProg > SLACK);
        }

        // x acquire: 4 tagged words/thread (ring slack -> usually ready)
        {
            const unsigned xe = (unsigned)(t + 1);
            const u64* xrow = xring + (size_t)(t & (RING - 1)) * HDIM;
            u64 w0 = 0, w1 = 0, w2 = 0, w3 = 0;
            bool d0 = false, d1 = false, d2 = false, d3 = false;
            while (!(d0 && d1 && d2 && d3)) {
                if (!d0) { w0 = agload64(xrow + tid);       d0 = ((unsigned)(w0 >> 32) == xe); }
                if (!d1) { w1 = agload64(xrow + tid + 256); d1 = ((unsigned)(w1 >> 32) == xe); }
                if (!d2) { w2 = agload64(xrow + tid + 512); d2 = ((unsigned)(w2 >> 32) == xe); }
                if (!d3) { w3 = agload64(xrow + tid + 768); d3 = ((unsigned)(w3 >> 32) == xe); }
            }
            xD[tid]       = __uint_as_float((unsigned)w0);
            xD[tid + 256] = __uint_as_float((unsigned)w1);
            xD[tid + 512] = __uint_as_float((unsigned)w2);
            xD[tid + 768] = __uint_as_float((unsigned)w3);
        }
        __syncthreads();

        // per-WG consumption progress (army WGs are not step-coupled)
        if (tid == 0) agstorei(progSelf, t + 1);

        // dots: 4 units x 2 rows x 4 chunks = 32 dot4/thread
        float aGF[4] = {0.f, 0.f, 0.f, 0.f};
        float aGN[4] = {0.f, 0.f, 0.f, 0.f};
#pragma unroll
        for (int m = 0; m < 4; ++m) {
            const float4 x4 = ((const float4*)xD)[q + 64 * m];
#pragma unroll
            for (int g = 0; g < 4; ++g) {
                aGF[g] += dot4(wiF[g][m], x4);
                aGN[g] += dot4(wiN[g][m], x4);
            }
        }

        // three-phase reduction for 4 units
#pragma unroll
        for (int g = 0; g < 4; ++g) {
            aGF[g] += __shfl_xor(aGF[g], 1, 64);
            aGN[g] += __shfl_xor(aGN[g], 1, 64);
        }
        const int s1 = q & 1;
        float bF0 = s1 ? aGF[1] : aGF[0];
        float bF1 = s1 ? aGF[3] : aGF[2];
        float bN0 = s1 ? aGN[1] : aGN[0];
        float bN1 = s1 ? aGN[3] : aGN[2];
        bF0 += __shfl_xor(bF0, 2, 64);
        bF1 += __shfl_xor(bF1, 2, 64);
        bN0 += __shfl_xor(bN0, 2, 64);
        bN1 += __shfl_xor(bN1, 2, 64);
        const int s2 = (q >> 1) & 1;
        float vGF = s2 ? bF1 : bF0;
        float vGN = s2 ? bN1 : bN0;
#pragma unroll
        for (int off = 4; off <= 32; off <<= 1) {
            vGF += __shfl_xor(vGF, off, 64);
            vGN += __shfl_xor(vGN, off, 64);
        }

        // publish: lane q<4 -> unit jb+q (static-index bias select)
        if (q < 4) {
            const int j = jb + q;
            u64* grow = giRing + (size_t)(t & (RING - 1)) * 2048;
            const float bf = s1 ? (s2 ? bIF[3] : bIF[1]) : (s2 ? bIF[2] : bIF[0]);
            const float bn = s1 ? (s2 ? bIN[3] : bIN[1]) : (s2 ? bIN[2] : bIN[0]);
            agstore64(grow + j,        pack(vGF + bf, t + 1));
            agstore64(grow + 1024 + j, pack(vGN + bn, t + 1));
        }
    }
}

// ================= kernels =================
__global__ __launch_bounds__(256, 2)   // 256-reg cap, 2 blocks/CU GUARANTEED
void mgu_pipe(const float* __restrict__ S,
              const float* __restrict__ h0,
              const float* __restrict__ w_ih0, const float* __restrict__ b_ih0,
              const float* __restrict__ w_hh0, const float* __restrict__ b_hh0,
              const float* __restrict__ w_ih_r, const float* __restrict__ b_ih_r,
              const float* __restrict__ w_hh_r, const float* __restrict__ b_hh_r,
              float* __restrict__ xbuf2, u64* __restrict__ ring0,
              u64* __restrict__ ring1, u64* __restrict__ gi1,
              u64* __restrict__ gi2, u64* __restrict__ htag,
              int* __restrict__ prog)
{
    __shared__ __align__(16) float s_h[2 * HDIM];   // rec: h / army: x
    __shared__ __align__(16) float s_x0[2 * 128];   // L0 S-row staging
    __shared__ float s_gi[2][16];                   // rec L>0 gi staging

    int* prog_gi1 = prog + 0;     // L1 gi consumption (single)
    int* prog_gi2 = prog + 16;    // L2 gi consumption (single)
    int* prog_a3  = prog + 64;    // army3 per-WG x consumption [64]
    int* prog_a4  = prog + 128;   // army4 per-WG x consumption [64]

    const int bid = blockIdx.x;
    if (bid < 128) {
        rec_layer<0>(s_h, s_x0, s_gi, S, h0,
                     w_ih0, b_ih0, w_hh0, b_hh0,
                     nullptr, ring0, nullptr,
                     htag, prog_a3, nullptr, bid);
    } else if (bid < 256) {
        rec_layer<1>(s_h, nullptr, s_gi, nullptr, h0 + HDIM,
                     nullptr, nullptr, w_hh_r, b_hh_r,
                     gi1, ring1, nullptr,
                     htag + 2 * HDIM, prog_a4, prog_gi1, bid - 128);
    } else if (bid < 384) {
        rec_layer<2>(s_h, nullptr, s_gi, nullptr, h0 + 2 * HDIM,
                     nullptr, nullptr, w_hh_r + 2048 * 1024, b_hh_r + 2048,
                     gi2, nullptr, xbuf2,
                     htag + 4 * HDIM, nullptr, prog_gi2, bid - 256);
    } else if (bid < 448) {
        army_layer(s_h, ring0, gi1, w_ih_r, b_ih_r,
                   prog_gi1, prog_a3 + (bid - 384), bid - 384);
    } else {
        army_layer(s_h, ring1, gi2, w_ih_r + 2048 * 1024, b_ih_r + 2048,
                   prog_gi2, prog_a4 + (bid - 448), bid - 448);
    }
}

__global__ __launch_bounds__(256)
void mgu_out(const float* __restrict__ x,       // [T, H]
             const float* __restrict__ w_out,   // [1, H]
             const float* __restrict__ b_out,   // [1]
             float* __restrict__ out)           // [T]
{
    const int wave = threadIdx.x >> 6;
    const int lane = threadIdx.x & 63;
    const int t = blockIdx.x * 4 + wave;
    float acc = 0.f;
#pragma unroll
    for (int m = 0; m < 4; ++m) {
        const int i4 = lane + 64 * m;
        const float4 x4 = ((const float4*)(x + (size_t)t * HDIM))[i4];
        const float4 w4 = ((const float4*)w_out)[i4];
        acc += dot4(x4, w4);
    }
#pragma unroll
    for (int off = 32; off > 0; off >>= 1) acc += __shfl_xor(acc, off, 64);
    if (lane == 0) out[t] = acc + b_out[0];
}

extern "C" void kernel_launch(void* const* d_in, const int* in_sizes, int n_in,
                              void* d_out, int out_size, void* d_ws, size_t ws_size,
                              hipStream_t stream) {
    const float* S      = (const float*)d_in[0];   // [8192,128]
    const float* h0     = (const float*)d_in[1];   // [3,1024]
    const float* w_ih0  = (const float*)d_in[2];   // [2048,128]
    const float* w_hh0  = (const float*)d_in[3];   // [2048,1024]
    const float* b_ih0  = (const float*)d_in[4];   // [2048]
    const float* b_hh0  = (const float*)d_in[5];   // [2048]
    const float* w_ih_r = (const float*)d_in[6];   // [2,2048,1024]
    const float* w_hh_r = (const float*)d_in[7];   // [2,2048,1024]
    const float* b_ih_r = (const float*)d_in[8];   // [2,2048]
    const float* b_hh_r = (const float*)d_in[9];   // [2,2048]
    const float* w_out  = (const float*)d_in[10];  // [1,1024]
    const float* b_out  = (const float*)d_in[11];  // [1]
    float* out = (float*)d_out;                    // [8192]

    char* ws = (char*)d_ws;
    float* xbuf2 = (float*)(ws);                        // 32 MB [T,H] f32
    u64*   ring0 = (u64*)(ws + (32u << 20));            // 1 MB  [RING,H] u64
    u64*   ring1 = (u64*)(ws + (33u << 20));            // 1 MB
    u64*   gi1   = (u64*)(ws + (34u << 20));            // 2 MB  [RING,2H] u64
    u64*   gi2   = (u64*)(ws + (36u << 20));            // 2 MB
    u64*   htag  = (u64*)(ws + (38u << 20));            // 3 x [2,H] u64
    int*   prog  = (int*)(ws + (38u << 20) + (64u << 10));  // 192 ints

    // No init kernel: all tags/progress use exact-match vs the 0xAA poison.
    mgu_pipe<<<512, 256, 0, stream>>>(S, h0, w_ih0, b_ih0, w_hh0, b_hh0,
                                      w_ih_r, b_ih_r, w_hh_r, b_hh_r,
                                      xbuf2, ring0, ring1, gi1, gi2,
                                      htag, prog);
    mgu_out<<<2048, 256, 0, stream>>>(xbuf2, w_out, b_out, out);
}